// Round 11
// baseline (282.502 us; speedup 1.0000x reference)
//
#include <hip/hip_runtime.h>

typedef unsigned int uint;
typedef unsigned short ushort;
typedef __attribute__((ext_vector_type(8))) short short8v;
typedef __attribute__((ext_vector_type(4))) float f32x4;

#define NBMAX 512      // max coarse buckets (bucket = 256 nodes, N <= 131072)
#define BSHIFT 8       // 256 nodes per bucket
#define CHUNK 64       // nodes per agg work-queue chunk

__device__ __forceinline__ ushort f2bf(float f) {
    uint u = __float_as_uint(f);
    u += 0x7fffu + ((u >> 16) & 1u);   // round-to-nearest-even
    return (ushort)(u >> 16);
}

// ---------------- binned CSR build ----------------
// Pass A: bin edges by coarse bucket (dst>>BSHIFT); record = src | locdst<<17 (4B).

__global__ void bucket_hist(const int* __restrict__ dst, int* __restrict__ bcnt,
                            int E, int nbk) {
    __shared__ int s[NBMAX];
    int t = threadIdx.x;
    for (int i = t; i < nbk; i += 256) s[i] = 0;
    __syncthreads();
    int i0 = blockIdx.x * 4096 + t;
#pragma unroll
    for (int k = 0; k < 16; ++k) {
        int i = i0 + k * 256;
        if (i < E) atomicAdd(&s[dst[i] >> BSHIFT], 1);
    }
    __syncthreads();
    for (int i = t; i < nbk; i += 256) if (s[i] > 0) atomicAdd(&bcnt[i], s[i]);
}

// single block, 512 threads: exclusive scan bcnt -> bstart (kept) and bcur (mutated later)
__global__ void bucket_scan(const int* __restrict__ bcnt, int* __restrict__ bstart,
                            int* __restrict__ bcur, int nbk) {
    __shared__ int s[512];
    int t = threadIdx.x;
    int v = (t < nbk) ? bcnt[t] : 0;
    s[t] = v;
    __syncthreads();
    for (int o = 1; o < 512; o <<= 1) {
        int tv = (t >= o) ? s[t - o] : 0;
        __syncthreads();
        s[t] += tv;
        __syncthreads();
    }
    if (t < nbk) {
        int ex = s[t] - v;
        bstart[t] = ex;
        bcur[t] = ex;
    }
}

__global__ void bucket_scatter(const int* __restrict__ src, const int* __restrict__ dst,
                               int* __restrict__ bcur, int* __restrict__ tsw, int E) {
    __shared__ int cnt[NBMAX];
    __shared__ int base[NBMAX];
    int t = threadIdx.x;
    for (int i = t; i < NBMAX; i += 256) cnt[i] = 0;
    __syncthreads();
    int i0 = blockIdx.x * 4096 + t;
    int p_[16], b_[16], r_[16];
#pragma unroll
    for (int k = 0; k < 16; ++k) {
        int i = i0 + k * 256;
        if (i < E) {
            int s = src[i], d = dst[i];
            int bb = d >> BSHIFT;
            b_[k] = bb;
            p_[k] = s | ((d & ((1 << BSHIFT) - 1)) << 17);
            r_[k] = atomicAdd(&cnt[bb], 1);
        } else {
            b_[k] = -1;
        }
    }
    __syncthreads();
    for (int i = t; i < NBMAX; i += 256) if (cnt[i] > 0) base[i] = atomicAdd(&bcur[i], cnt[i]);
    __syncthreads();
#pragma unroll
    for (int k = 0; k < 16; ++k) {
        if (b_[k] >= 0) {
            int p = base[b_[k]] + r_[k];
            tsw[p] = p_[k];
        }
    }
}

// Pass B: one block per bucket. LDS counting-sort by local dst; the LDS histogram IS
// the in-degree -> emits dinv, rp, self-loops, and the bucket's contiguous edata region.
__global__ void sort_bucket(const int* __restrict__ tsw, const int* __restrict__ bstart,
                            float* __restrict__ dinv, int* __restrict__ rp,
                            int* __restrict__ edata, int N, int E, int nbk) {
    __shared__ int cnt[256];
    __shared__ int cursor[256];
    int b = blockIdx.x;
    int t = threadIdx.x;
    int estart = bstart[b];
    int eend = (b + 1 < nbk) ? bstart[b + 1] : E;

    cnt[t] = 0;
    __syncthreads();
    for (int i = estart + t; i < eend; i += 256) {
        atomicAdd(&cnt[(uint)tsw[i] >> 17], 1);
    }
    __syncthreads();

    int node = (b << BSHIFT) + t;
    int self = (node < N) ? 1 : 0;
    int deg = cnt[t];
    int v = deg + self;
    cursor[t] = v;
    __syncthreads();
    for (int o = 1; o < 256; o <<= 1) {
        int tv = (t >= o) ? cursor[t - o] : 0;
        __syncthreads();
        cursor[t] += tv;
        __syncthreads();
    }
    int ex = cursor[t] - v;                       // exclusive local offset
    int gbase = estart + (b << BSHIFT);           // edges + self loops before this bucket

    if (node < N) {
        dinv[node] = rsqrtf((float)(deg + 1));    // + self loop
        rp[node] = gbase + ex;
        edata[gbase + ex] = node;                 // self loop at slot 0 (src == dst)
    }
    if (b == nbk - 1 && t == 0) rp[N] = E + N;
    cursor[t] = ex + self;
    __syncthreads();

    for (int i = estart + t; i < eend; i += 256) {
        uint rec = (uint)tsw[i];
        int pos = gbase + atomicAdd(&cursor[rec >> 17], 1);
        edata[pos] = (int)(rec & 0x1FFFFu);
    }
}

// ---------------- W prep (transpose/convert/swizzle) + bcnt/queue zeroing ----------------

__global__ void prep_w(const float* __restrict__ W1, const float* __restrict__ W2,
                       ushort* __restrict__ Wt1s, ushort* __restrict__ Wt2s,
                       int* __restrict__ bcnt, int* __restrict__ qh) {
    int t = blockIdx.x * 256 + threadIdx.x;
    if (t < NBMAX) bcnt[t] = 0;
    if (t < 8) qh[t] = 0;
    int total = gridDim.x * 256;
    for (int idx = t; idx < 128 * 128; idx += total) {
        int nn = idx >> 7, kk = idx & 127;
        uint byte = (uint)nn * 256u + (uint)kk * 2u;
        byte ^= (uint)((nn & 7) << 4);
        Wt1s[byte >> 1] = f2bf(W1[kk * 128 + nn]);
    }
    for (int idx = t; idx < 64 * 128; idx += total) {
        int nn = idx >> 7, kk = idx & 127;
        uint byte = (uint)nn * 256u + (uint)kk * 2u;
        byte ^= (uint)((nn & 7) << 4);
        Wt2s[byte >> 1] = f2bf(W2[kk * 64 + nn]);
    }
}

// ---------------- MFMA GEMM: slab-major out H[s][row][32] = dinv[row]*(X@W), s=col>>5 ----------------
// Zeroes the pad row (index n) of each slab from blockIdx 0.
// mfma_f32_16x16x32_bf16: A row=lane&15, k=(lane>>4)*8+i ; B col=lane&15, same k ;
// D col=lane&15, row=(lane>>4)*4+reg
// IN_BF16 input is slab-major [4][n][32] (strideA); fp32 input is row-major [n][128].

template <int NCOLS, bool IN_BF16>
__launch_bounds__(256)
__global__ void gemm_mfma(const void* __restrict__ Xv, const ushort* __restrict__ Wimg,
                          ushort* __restrict__ H, const float* __restrict__ dinv,
                          int n, int strideA, int strideH) {
    constexpr int NT = NCOLS / 16;
    if (blockIdx.x == 0 && threadIdx.x < NCOLS)
        H[(size_t)(threadIdx.x >> 5) * strideH + (size_t)n * 32 + (threadIdx.x & 31)] = 0;
    __shared__ ushort sW[NCOLS * 128];
    {
        const uint4* src = (const uint4*)Wimg;
        uint4* dst = (uint4*)sW;
        constexpr int NV = NCOLS * 128 * 2 / 16;
        for (int i = threadIdx.x; i < NV; i += 256) dst[i] = src[i];
    }
    __syncthreads();

    const int w  = threadIdx.x >> 6;
    const int l  = threadIdx.x & 63;
    const int lm = l & 15, lk = l >> 4;
    const int row_base = blockIdx.x * 128 + w * 32;

    f32x4 acc[2][NT];
#pragma unroll
    for (int mt = 0; mt < 2; ++mt)
#pragma unroll
        for (int nt = 0; nt < NT; ++nt) {
            f32x4 z = {0.f, 0.f, 0.f, 0.f};
            acc[mt][nt] = z;
        }

    int r0 = row_base + lm;
    int r1 = row_base + 16 + lm;
    int r0c = r0 < n ? r0 : n - 1;
    int r1c = r1 < n ? r1 : n - 1;

#pragma unroll
    for (int kb = 0; kb < 4; ++kb) {
        short8v a0, a1;
        if constexpr (IN_BF16) {
            const ushort* X = (const ushort*)Xv;
            a0 = *(const short8v*)(X + (size_t)kb * strideA + (size_t)r0c * 32 + lk * 8);
            a1 = *(const short8v*)(X + (size_t)kb * strideA + (size_t)r1c * 32 + lk * 8);
        } else {
            const float* X = (const float*)Xv;
            const float* p0 = X + (size_t)r0c * 128 + kb * 32 + lk * 8;
            const float* p1 = X + (size_t)r1c * 128 + kb * 32 + lk * 8;
            float4 u0 = *(const float4*)p0;
            float4 v0 = *(const float4*)(p0 + 4);
            float4 u1 = *(const float4*)p1;
            float4 v1 = *(const float4*)(p1 + 4);
            a0[0] = (short)f2bf(u0.x); a0[1] = (short)f2bf(u0.y);
            a0[2] = (short)f2bf(u0.z); a0[3] = (short)f2bf(u0.w);
            a0[4] = (short)f2bf(v0.x); a0[5] = (short)f2bf(v0.y);
            a0[6] = (short)f2bf(v0.z); a0[7] = (short)f2bf(v0.w);
            a1[0] = (short)f2bf(u1.x); a1[1] = (short)f2bf(u1.y);
            a1[2] = (short)f2bf(u1.z); a1[3] = (short)f2bf(u1.w);
            a1[4] = (short)f2bf(v1.x); a1[5] = (short)f2bf(v1.y);
            a1[6] = (short)f2bf(v1.z); a1[7] = (short)f2bf(v1.w);
        }
#pragma unroll
        for (int nt = 0; nt < NT; ++nt) {
            int nn = nt * 16 + lm;
            uint byte = (uint)nn * 256u + (uint)kb * 64u + (uint)lk * 16u;
            byte ^= (uint)((nn & 7) << 4);
            short8v b = *(const short8v*)((const char*)sW + byte);
            acc[0][nt] = __builtin_amdgcn_mfma_f32_16x16x32_bf16(a0, b, acc[0][nt], 0, 0, 0);
            acc[1][nt] = __builtin_amdgcn_mfma_f32_16x16x32_bf16(a1, b, acc[1][nt], 0, 0, 0);
        }
    }

    float dvs[2][4];
#pragma unroll
    for (int mt = 0; mt < 2; ++mt)
#pragma unroll
        for (int r = 0; r < 4; ++r) {
            int row = row_base + mt * 16 + lk * 4 + r;
            dvs[mt][r] = (row < n) ? dinv[row] : 0.f;
        }
#pragma unroll
    for (int mt = 0; mt < 2; ++mt)
#pragma unroll
        for (int nt = 0; nt < NT; ++nt)
#pragma unroll
            for (int r = 0; r < 4; ++r) {
                int row = row_base + mt * 16 + lk * 4 + r;
                if (row < n) {
                    size_t off = (size_t)(nt >> 1) * strideH + (size_t)row * 32 + (nt & 1) * 16 + lm;
                    H[off] = f2bf(acc[mt][nt][r] * dvs[mt][r]);
                }
            }
}

// ---------------- aggregation: XCD-owned slabs + work-stealing queues ----------------
// H slab-major [NSLAB][N+1][32] bf16, zero pad row at N. Rows pre-scaled by dinv[src].
// Block reads its hardware XCC_ID, prefers the slab owned by its XCD group, pops a
// 64-node chunk from that slab's queue, steals from others when empty (coverage
// guaranteed; FP order per node fixed -> deterministic output).
// 16-lane quarter per node; lane c owns dims {2c,2c+1}; 16-slot batches -> 16 loads in flight.

template <int NSLAB, bool RELU, bool OUT_BF16>
__launch_bounds__(256)
__global__ void agg_slab(const ushort* __restrict__ H, const int* __restrict__ rp,
                         const int* __restrict__ edata, const float* __restrict__ dinv,
                         const float* __restrict__ bias, void* __restrict__ outv,
                         int* __restrict__ qh, int N, int nchunks,
                         int strideH, int strideO) {
    __shared__ int sc[2];
    if (threadIdx.x == 0) {
        uint xcc = 0;
        asm volatile("s_getreg_b32 %0, hwreg(HW_REG_XCC_ID)" : "=s"(xcc));
        int pref = (NSLAB == 4) ? (int)((xcc >> 1) & 3) : (int)((xcc >> 2) & 1);
        int chunk = -1, slab = 0;
#pragma unroll
        for (int k = 0; k < NSLAB; ++k) {
            int q = (pref + k) & (NSLAB - 1);
            int v = atomicAdd(&qh[q], 1);
            if (v < nchunks) { chunk = v; slab = q; break; }
        }
        sc[0] = chunk; sc[1] = slab;
    }
    __syncthreads();
    const int chunk = sc[0], slab = sc[1];
    if (chunk < 0) return;

    const int lane = threadIdx.x & 63;
    const int c = lane & 15;
    const int qb = lane & 48;                     // quarter base within wave
    const int quarter = threadIdx.x >> 4;         // 0..15 within block
    const ushort* Hs = H + (size_t)slab * strideH;

    for (int r = 0; r < CHUNK / 16; ++r) {
        int node = chunk * CHUNK + r * 16 + quarter;
        if (node >= N) continue;
        int e = rp[node], end = rp[node + 1];
        float a0 = 0.f, a1 = 0.f;
        for (; e < end; e += 16) {
            int idx = e + c;
            int md = (idx < end) ? edata[idx] : N;   // pad -> zero row
#pragma unroll
            for (int j = 0; j < 16; ++j) {
                int si = __shfl(md, qb + j);
                uint hv = *(const uint*)&Hs[(size_t)si * 32 + c * 2];
                a0 += __uint_as_float(hv << 16);
                a1 += __uint_as_float(hv & 0xffff0000u);
            }
        }
        float dg = dinv[node];
        float2 bv = *(const float2*)&bias[slab * 32 + c * 2];
        a0 = dg * a0 + bv.x;
        a1 = dg * a1 + bv.y;
        if (RELU) { a0 = fmaxf(a0, 0.f); a1 = fmaxf(a1, 0.f); }
        if (OUT_BF16) {
            ushort* o = (ushort*)outv;
            uint pk = (uint)f2bf(a0) | ((uint)f2bf(a1) << 16);
            *(uint*)&o[(size_t)slab * strideO + (size_t)node * 32 + c * 2] = pk;
        } else {
            float* o = (float*)outv;
            *(float2*)&o[(size_t)node * 64 + slab * 32 + c * 2] = make_float2(a0, a1);
        }
    }
}

__global__ void zero_out(float* __restrict__ out, int n) {
    int i = blockIdx.x * 256 + threadIdx.x;
    if (i < n) out[i] = 0.f;
}

// ---------------- launch ----------------

extern "C" void kernel_launch(void* const* d_in, const int* in_sizes, int n_in,
                              void* d_out, int out_size, void* d_ws, size_t ws_size,
                              hipStream_t stream) {
    const float* x  = (const float*)d_in[0];
    const int*   ei = (const int*)d_in[1];
    const float* W1 = (const float*)d_in[2];
    const float* b1 = (const float*)d_in[3];
    const float* W2 = (const float*)d_in[4];
    const float* b2 = (const float*)d_in[5];
    float* out = (float*)d_out;

    const int N = in_sizes[0] / 128;
    const int E = in_sizes[1] / 2;
    const int* srcp = ei;
    const int* dstp = ei + E;

    char* base = (char*)d_ws;
    size_t off = 0;
    auto alloc = [&](size_t bytes) -> void* {
        void* p = base + off;
        off += (bytes + 15) & ~(size_t)15;
        return p;
    };
    ushort* H1    = (ushort*)alloc((size_t)(N + 1) * 128 * 2);  // [4][N+1][32]; H2=[2][N+1][32] aliases
    ushort* A1    = (ushort*)alloc((size_t)N * 128 * 2);        // [4][N][32]; aliases tsw
    ushort* Wt1s  = (ushort*)alloc(128 * 128 * 2);
    ushort* Wt2s  = (ushort*)alloc(64 * 128 * 2);
    float*  dinv  = (float*)alloc((size_t)N * 4);
    int*    rp    = (int*)alloc((size_t)(N + 1) * 4);
    int*    bcnt  = (int*)alloc(NBMAX * 4);
    int*    bstart= (int*)alloc(NBMAX * 4);
    int*    bcur  = (int*)alloc(NBMAX * 4);
    int*    qh    = (int*)alloc(8 * 4);            // 4 queues (layer1) + 2 queues (layer2)
    int*    edata = (int*)alloc((size_t)(E + N) * 4);
    ushort* H2    = H1;   // reuse layer-1 buffer as [2][N+1][32]

    int* tsw = (int*)A1;   // E records of 4B; needs E*4 <= N*256

    const int strideH = (N + 1) * 32;   // slab stride for H1/H2
    const int strideA = N * 32;         // slab stride for A1

    int nbk = (N + (1 << BSHIFT) - 1) >> BSHIFT;
    if (off > ws_size || (size_t)E * 4 > (size_t)N * 256 || N > (1 << 17) || nbk > NBMAX) {
        zero_out<<<(out_size + 255) / 256, 256, 0, stream>>>(out, out_size);
        return;
    }
    int nchunk = (E + 4095) / 4096;
    int nch = (N + CHUNK - 1) / CHUNK;

    prep_w<<<32, 256, 0, stream>>>(W1, W2, Wt1s, Wt2s, bcnt, qh);
    bucket_hist<<<nchunk, 256, 0, stream>>>(dstp, bcnt, E, nbk);
    bucket_scan<<<1, 512, 0, stream>>>(bcnt, bstart, bcur, nbk);
    bucket_scatter<<<nchunk, 256, 0, stream>>>(srcp, dstp, bcur, tsw, E);
    sort_bucket<<<nbk, 256, 0, stream>>>(tsw, bstart, dinv, rp, edata, N, E, nbk);

    gemm_mfma<128, false><<<(N + 127) / 128, 256, 0, stream>>>(x, Wt1s, H1, dinv, N, 0, strideH);
    agg_slab<4, true, true><<<4 * nch, 256, 0, stream>>>(
        H1, rp, edata, dinv, b1, A1, qh, N, nch, strideH, strideA);
    gemm_mfma<64, true><<<(N + 127) / 128, 256, 0, stream>>>(A1, Wt2s, H2, dinv, N, strideA, strideH);
    agg_slab<2, false, false><<<2 * nch, 256, 0, stream>>>(
        H2, rp, edata, dinv, b2, out, qh + 4, N, nch, strideH, 0);
}

// Round 12
// 198.296 us; speedup vs baseline: 1.4246x; 1.4246x over previous
//
#include <hip/hip_runtime.h>

typedef unsigned int uint;
typedef unsigned short ushort;
typedef __attribute__((ext_vector_type(8))) short short8v;
typedef __attribute__((ext_vector_type(4))) float f32x4;

#define NBMAX 512      // max coarse buckets (bucket = 256 nodes, N <= 131072)
#define BSHIFT 8       // 256 nodes per bucket

__device__ __forceinline__ ushort f2bf(float f) {
    uint u = __float_as_uint(f);
    u += 0x7fffu + ((u >> 16) & 1u);   // round-to-nearest-even
    return (ushort)(u >> 16);
}

// ---------------- binned CSR build ----------------
// Pass A: bin edges by coarse bucket (dst>>BSHIFT); record = src | locdst<<17 (4B).

__global__ void bucket_hist(const int* __restrict__ dst, int* __restrict__ bcnt,
                            int E, int nbk) {
    __shared__ int s[NBMAX];
    int t = threadIdx.x;
    for (int i = t; i < nbk; i += 256) s[i] = 0;
    __syncthreads();
    int i0 = blockIdx.x * 4096 + t;
#pragma unroll
    for (int k = 0; k < 16; ++k) {
        int i = i0 + k * 256;
        if (i < E) atomicAdd(&s[dst[i] >> BSHIFT], 1);
    }
    __syncthreads();
    for (int i = t; i < nbk; i += 256) if (s[i] > 0) atomicAdd(&bcnt[i], s[i]);
}

// single block, 512 threads: exclusive scan bcnt -> bstart (kept) and bcur (mutated later)
__global__ void bucket_scan(const int* __restrict__ bcnt, int* __restrict__ bstart,
                            int* __restrict__ bcur, int nbk) {
    __shared__ int s[512];
    int t = threadIdx.x;
    int v = (t < nbk) ? bcnt[t] : 0;
    s[t] = v;
    __syncthreads();
    for (int o = 1; o < 512; o <<= 1) {
        int tv = (t >= o) ? s[t - o] : 0;
        __syncthreads();
        s[t] += tv;
        __syncthreads();
    }
    if (t < nbk) {
        int ex = s[t] - v;
        bstart[t] = ex;
        bcur[t] = ex;
    }
}

__global__ void bucket_scatter(const int* __restrict__ src, const int* __restrict__ dst,
                               int* __restrict__ bcur, int* __restrict__ tsw, int E) {
    __shared__ int cnt[NBMAX];
    __shared__ int base[NBMAX];
    int t = threadIdx.x;
    for (int i = t; i < NBMAX; i += 256) cnt[i] = 0;
    __syncthreads();
    int i0 = blockIdx.x * 4096 + t;
    int p_[16], b_[16], r_[16];
#pragma unroll
    for (int k = 0; k < 16; ++k) {
        int i = i0 + k * 256;
        if (i < E) {
            int s = src[i], d = dst[i];
            int bb = d >> BSHIFT;
            b_[k] = bb;
            p_[k] = s | ((d & ((1 << BSHIFT) - 1)) << 17);
            r_[k] = atomicAdd(&cnt[bb], 1);
        } else {
            b_[k] = -1;
        }
    }
    __syncthreads();
    for (int i = t; i < NBMAX; i += 256) if (cnt[i] > 0) base[i] = atomicAdd(&bcur[i], cnt[i]);
    __syncthreads();
#pragma unroll
    for (int k = 0; k < 16; ++k) {
        if (b_[k] >= 0) {
            int p = base[b_[k]] + r_[k];
            tsw[p] = p_[k];
        }
    }
}

// Pass B: one block per bucket. LDS counting-sort by local dst; the LDS histogram IS
// the in-degree -> emits dinv, rp, self-loops, and the bucket's contiguous edata region.
__global__ void sort_bucket(const int* __restrict__ tsw, const int* __restrict__ bstart,
                            float* __restrict__ dinv, int* __restrict__ rp,
                            int* __restrict__ edata, int N, int E, int nbk) {
    __shared__ int cnt[256];
    __shared__ int cursor[256];
    int b = blockIdx.x;
    int t = threadIdx.x;
    int estart = bstart[b];
    int eend = (b + 1 < nbk) ? bstart[b + 1] : E;

    cnt[t] = 0;
    __syncthreads();
    for (int i = estart + t; i < eend; i += 256) {
        atomicAdd(&cnt[(uint)tsw[i] >> 17], 1);
    }
    __syncthreads();

    int node = (b << BSHIFT) + t;
    int self = (node < N) ? 1 : 0;
    int deg = cnt[t];
    int v = deg + self;
    cursor[t] = v;
    __syncthreads();
    for (int o = 1; o < 256; o <<= 1) {
        int tv = (t >= o) ? cursor[t - o] : 0;
        __syncthreads();
        cursor[t] += tv;
        __syncthreads();
    }
    int ex = cursor[t] - v;                       // exclusive local offset
    int gbase = estart + (b << BSHIFT);           // edges + self loops before this bucket

    if (node < N) {
        dinv[node] = rsqrtf((float)(deg + 1));    // + self loop
        rp[node] = gbase + ex;
        edata[gbase + ex] = node;                 // self loop at slot 0 (src == dst)
    }
    if (b == nbk - 1 && t == 0) rp[N] = E + N;
    cursor[t] = ex + self;
    __syncthreads();

    for (int i = estart + t; i < eend; i += 256) {
        uint rec = (uint)tsw[i];
        int pos = gbase + atomicAdd(&cursor[rec >> 17], 1);
        edata[pos] = (int)(rec & 0x1FFFFu);
    }
}

// ---------------- W pre-transpose/convert/swizzle + bcnt zeroing (runs first) ----------------

__global__ void prep_w(const float* __restrict__ W1, const float* __restrict__ W2,
                       ushort* __restrict__ Wt1s, ushort* __restrict__ Wt2s,
                       int* __restrict__ bcnt) {
    int t = blockIdx.x * 256 + threadIdx.x;
    if (t < NBMAX) bcnt[t] = 0;
    int total = gridDim.x * 256;
    for (int idx = t; idx < 128 * 128; idx += total) {
        int nn = idx >> 7, kk = idx & 127;
        uint byte = (uint)nn * 256u + (uint)kk * 2u;
        byte ^= (uint)((nn & 7) << 4);
        Wt1s[byte >> 1] = f2bf(W1[kk * 128 + nn]);
    }
    for (int idx = t; idx < 64 * 128; idx += total) {
        int nn = idx >> 7, kk = idx & 127;
        uint byte = (uint)nn * 256u + (uint)kk * 2u;
        byte ^= (uint)((nn & 7) << 4);
        Wt2s[byte >> 1] = f2bf(W2[kk * 64 + nn]);
    }
}

// ---------------- MFMA GEMM: H[row][0..NCOLS) = dinv[row] * (X[row] @ W), row-major ----------------
// Also zeroes the pad row at index n (blockIdx 0) so aggs can gather it harmlessly.
// mfma_f32_16x16x32_bf16: A row=lane&15, k=(lane>>4)*8+i ; B col=lane&15, same k ;
// D col=lane&15, row=(lane>>4)*4+reg

template <int NCOLS, bool IN_BF16>
__launch_bounds__(256)
__global__ void gemm_mfma(const void* __restrict__ Xv, const ushort* __restrict__ Wimg,
                          ushort* __restrict__ H, const float* __restrict__ dinv, int n) {
    constexpr int NT = NCOLS / 16;
    if (blockIdx.x == 0 && threadIdx.x < NCOLS) H[(size_t)n * NCOLS + threadIdx.x] = 0;
    __shared__ ushort sW[NCOLS * 128];
    {
        const uint4* src = (const uint4*)Wimg;
        uint4* dst = (uint4*)sW;
        constexpr int NV = NCOLS * 128 * 2 / 16;
        for (int i = threadIdx.x; i < NV; i += 256) dst[i] = src[i];
    }
    __syncthreads();

    const int w  = threadIdx.x >> 6;
    const int l  = threadIdx.x & 63;
    const int lm = l & 15, lk = l >> 4;
    const int row_base = blockIdx.x * 128 + w * 32;

    f32x4 acc[2][NT];
#pragma unroll
    for (int mt = 0; mt < 2; ++mt)
#pragma unroll
        for (int nt = 0; nt < NT; ++nt) {
            f32x4 z = {0.f, 0.f, 0.f, 0.f};
            acc[mt][nt] = z;
        }

    int r0 = row_base + lm;
    int r1 = row_base + 16 + lm;
    int r0c = r0 < n ? r0 : n - 1;
    int r1c = r1 < n ? r1 : n - 1;

#pragma unroll
    for (int kb = 0; kb < 4; ++kb) {
        short8v a0, a1;
        if constexpr (IN_BF16) {
            const ushort* X = (const ushort*)Xv;
            a0 = *(const short8v*)(X + (size_t)r0c * 128 + kb * 32 + lk * 8);
            a1 = *(const short8v*)(X + (size_t)r1c * 128 + kb * 32 + lk * 8);
        } else {
            const float* X = (const float*)Xv;
            const float* p0 = X + (size_t)r0c * 128 + kb * 32 + lk * 8;
            const float* p1 = X + (size_t)r1c * 128 + kb * 32 + lk * 8;
            float4 u0 = *(const float4*)p0;
            float4 v0 = *(const float4*)(p0 + 4);
            float4 u1 = *(const float4*)p1;
            float4 v1 = *(const float4*)(p1 + 4);
            a0[0] = (short)f2bf(u0.x); a0[1] = (short)f2bf(u0.y);
            a0[2] = (short)f2bf(u0.z); a0[3] = (short)f2bf(u0.w);
            a0[4] = (short)f2bf(v0.x); a0[5] = (short)f2bf(v0.y);
            a0[6] = (short)f2bf(v0.z); a0[7] = (short)f2bf(v0.w);
            a1[0] = (short)f2bf(u1.x); a1[1] = (short)f2bf(u1.y);
            a1[2] = (short)f2bf(u1.z); a1[3] = (short)f2bf(u1.w);
            a1[4] = (short)f2bf(v1.x); a1[5] = (short)f2bf(v1.y);
            a1[6] = (short)f2bf(v1.z); a1[7] = (short)f2bf(v1.w);
        }
#pragma unroll
        for (int nt = 0; nt < NT; ++nt) {
            int nn = nt * 16 + lm;
            uint byte = (uint)nn * 256u + (uint)kb * 64u + (uint)lk * 16u;
            byte ^= (uint)((nn & 7) << 4);
            short8v b = *(const short8v*)((const char*)sW + byte);
            acc[0][nt] = __builtin_amdgcn_mfma_f32_16x16x32_bf16(a0, b, acc[0][nt], 0, 0, 0);
            acc[1][nt] = __builtin_amdgcn_mfma_f32_16x16x32_bf16(a1, b, acc[1][nt], 0, 0, 0);
        }
    }

    // dinv pre-scale per row, store row-major
    float dvs[2][4];
#pragma unroll
    for (int mt = 0; mt < 2; ++mt)
#pragma unroll
        for (int r = 0; r < 4; ++r) {
            int row = row_base + mt * 16 + lk * 4 + r;
            dvs[mt][r] = (row < n) ? dinv[row] : 0.f;
        }
#pragma unroll
    for (int mt = 0; mt < 2; ++mt)
#pragma unroll
        for (int nt = 0; nt < NT; ++nt)
#pragma unroll
            for (int r = 0; r < 4; ++r) {
                int row = row_base + mt * 16 + lk * 4 + r;
                if (row < n) H[(size_t)row * NCOLS + nt * 16 + lm] = f2bf(acc[mt][nt][r] * dvs[mt][r]);
            }
}

// ---------------- aggregation: rows pre-scaled by dinv[src]; pure adds in the loop ----------------
// H is [N+1][D] bf16 row-major with a zero row at index N (padding-lane target).
// out[node] = dinv[node] * sum_e H[src_e] + bias.
// agg128: one node per 16-lane QUARTER-wave; lane owns dims [c*8, c*8+8) via one
// uint4 (16B) load per edge. 16-slot batches; 16 loads in flight covering 64 edge-rows.

template <bool RELU>
__launch_bounds__(256)
__global__ void agg128(const ushort* __restrict__ H, const int* __restrict__ rp,
                       const int* __restrict__ edata, const float* __restrict__ dinv,
                       const float* __restrict__ bias, ushort* __restrict__ out, int N) {
    const int lane = threadIdx.x & 63;
    const int q = lane >> 4;                      // quarter 0..3
    const int c = lane & 15;                      // lane in quarter
    const int node = blockIdx.x * 16 + ((threadIdx.x >> 6) << 2) + q;
    if (node >= N) return;                        // whole quarter exits together
    int e = rp[node], end = rp[node + 1];
    float a0 = 0.f, a1 = 0.f, a2 = 0.f, a3 = 0.f;
    float a4 = 0.f, a5 = 0.f, a6 = 0.f, a7 = 0.f;

    for (; e < end; e += 16) {
        int idx = e + c;
        int md = (idx < end) ? edata[idx] : N;    // zero row for padding slots
#pragma unroll
        for (int j = 0; j < 16; ++j) {
            int si = __shfl(md, (q << 4) + j);
            uint4 hv = *(const uint4*)&H[(size_t)si * 128 + c * 8];
            a0 += __uint_as_float(hv.x << 16);
            a1 += __uint_as_float(hv.x & 0xffff0000u);
            a2 += __uint_as_float(hv.y << 16);
            a3 += __uint_as_float(hv.y & 0xffff0000u);
            a4 += __uint_as_float(hv.z << 16);
            a5 += __uint_as_float(hv.z & 0xffff0000u);
            a6 += __uint_as_float(hv.w << 16);
            a7 += __uint_as_float(hv.w & 0xffff0000u);
        }
    }
    float dg = dinv[node];
    float4 bv0 = *(const float4*)&bias[c * 8];
    float4 bv1 = *(const float4*)&bias[c * 8 + 4];
    a0 = dg * a0 + bv0.x; a1 = dg * a1 + bv0.y;
    a2 = dg * a2 + bv0.z; a3 = dg * a3 + bv0.w;
    a4 = dg * a4 + bv1.x; a5 = dg * a5 + bv1.y;
    a6 = dg * a6 + bv1.z; a7 = dg * a7 + bv1.w;
    if (RELU) {
        a0 = fmaxf(a0, 0.f); a1 = fmaxf(a1, 0.f);
        a2 = fmaxf(a2, 0.f); a3 = fmaxf(a3, 0.f);
        a4 = fmaxf(a4, 0.f); a5 = fmaxf(a5, 0.f);
        a6 = fmaxf(a6, 0.f); a7 = fmaxf(a7, 0.f);
    }
    uint4 pk;
    pk.x = (uint)f2bf(a0) | ((uint)f2bf(a1) << 16);
    pk.y = (uint)f2bf(a2) | ((uint)f2bf(a3) << 16);
    pk.z = (uint)f2bf(a4) | ((uint)f2bf(a5) << 16);
    pk.w = (uint)f2bf(a6) | ((uint)f2bf(a7) << 16);
    *(uint4*)&out[(size_t)node * 128 + c * 8] = pk;
}

// agg64: one node per 16-lane QUARTER (16 lanes x uint2 = full 128B row); fp32 out.
__launch_bounds__(256)
__global__ void agg64(const ushort* __restrict__ H, const int* __restrict__ rp,
                      const int* __restrict__ edata, const float* __restrict__ dinv,
                      const float* __restrict__ bias, float* __restrict__ out, int N) {
    const int lane = threadIdx.x & 63;
    const int qb = lane & 48;                     // quarter base within wave
    const int c = lane & 15;
    const int node = blockIdx.x * 16 + (threadIdx.x >> 4);
    if (node >= N) return;                        // whole quarter exits together
    int e = rp[node], end = rp[node + 1];
    float a0 = 0.f, a1 = 0.f, a2 = 0.f, a3 = 0.f;

    for (; e < end; e += 16) {
        int idx = e + c;
        int md = (idx < end) ? edata[idx] : N;    // all 16 lanes load metadata
#pragma unroll
        for (int j = 0; j < 16; ++j) {
            int si = __shfl(md, qb + j);
            uint2 hv = *(const uint2*)&H[(size_t)si * 64 + c * 4];
            a0 += __uint_as_float(hv.x << 16);
            a1 += __uint_as_float(hv.x & 0xffff0000u);
            a2 += __uint_as_float(hv.y << 16);
            a3 += __uint_as_float(hv.y & 0xffff0000u);
        }
    }
    float dg = dinv[node];
    float4 bv = *(const float4*)&bias[c * 4];
    a0 = dg * a0 + bv.x; a1 = dg * a1 + bv.y;
    a2 = dg * a2 + bv.z; a3 = dg * a3 + bv.w;
    *(float4*)&out[(size_t)node * 64 + c * 4] = make_float4(a0, a1, a2, a3);
}

__global__ void zero_out(float* __restrict__ out, int n) {
    int i = blockIdx.x * 256 + threadIdx.x;
    if (i < n) out[i] = 0.f;
}

// ---------------- launch ----------------

extern "C" void kernel_launch(void* const* d_in, const int* in_sizes, int n_in,
                              void* d_out, int out_size, void* d_ws, size_t ws_size,
                              hipStream_t stream) {
    const float* x  = (const float*)d_in[0];
    const int*   ei = (const int*)d_in[1];
    const float* W1 = (const float*)d_in[2];
    const float* b1 = (const float*)d_in[3];
    const float* W2 = (const float*)d_in[4];
    const float* b2 = (const float*)d_in[5];
    float* out = (float*)d_out;

    const int N = in_sizes[0] / 128;
    const int E = in_sizes[1] / 2;
    const int* srcp = ei;
    const int* dstp = ei + E;

    char* base = (char*)d_ws;
    size_t off = 0;
    auto alloc = [&](size_t bytes) -> void* {
        void* p = base + off;
        off += (bytes + 15) & ~(size_t)15;
        return p;
    };
    ushort* H1    = (ushort*)alloc((size_t)(N + 1) * 128 * 2);  // [N+1][128]; H2=[N+1][64] aliases
    ushort* A1    = (ushort*)alloc((size_t)N * 128 * 2);        // [N][128]; aliases tsw
    ushort* Wt1s  = (ushort*)alloc(128 * 128 * 2);
    ushort* Wt2s  = (ushort*)alloc(64 * 128 * 2);
    float*  dinv  = (float*)alloc((size_t)N * 4);
    int*    rp    = (int*)alloc((size_t)(N + 1) * 4);
    int*    bcnt  = (int*)alloc(NBMAX * 4);
    int*    bstart= (int*)alloc(NBMAX * 4);
    int*    bcur  = (int*)alloc(NBMAX * 4);
    int*    edata = (int*)alloc((size_t)(E + N) * 4);
    ushort* H2    = H1;   // reuse layer-1 buffer as [N+1][64]

    int* tsw = (int*)A1;   // E records of 4B; needs E*4 <= N*256

    int nbk = (N + (1 << BSHIFT) - 1) >> BSHIFT;
    if (off > ws_size || (size_t)E * 4 > (size_t)N * 256 || N > (1 << 17) || nbk > NBMAX) {
        zero_out<<<(out_size + 255) / 256, 256, 0, stream>>>(out, out_size);
        return;
    }
    int nchunk = (E + 4095) / 4096;

    prep_w<<<32, 256, 0, stream>>>(W1, W2, Wt1s, Wt2s, bcnt);   // also zeroes bcnt
    bucket_hist<<<nchunk, 256, 0, stream>>>(dstp, bcnt, E, nbk);
    bucket_scan<<<1, 512, 0, stream>>>(bcnt, bstart, bcur, nbk);
    bucket_scatter<<<nchunk, 256, 0, stream>>>(srcp, dstp, bcur, tsw, E);
    sort_bucket<<<nbk, 256, 0, stream>>>(tsw, bstart, dinv, rp, edata, N, E, nbk);

    gemm_mfma<128, false><<<(N + 127) / 128, 256, 0, stream>>>(x, Wt1s, H1, dinv, N);
    agg128<true><<<(N + 15) / 16, 256, 0, stream>>>(H1, rp, edata, dinv, b1, A1, N);
    gemm_mfma<64, true><<<(N + 127) / 128, 256, 0, stream>>>(A1, Wt2s, H2, dinv, N);
    agg64<<<(N + 15) / 16, 256, 0, stream>>>(H2, rp, edata, dinv, b2, out, N);
}

// Round 13
// 191.324 us; speedup vs baseline: 1.4766x; 1.0364x over previous
//
#include <hip/hip_runtime.h>

typedef unsigned int uint;
typedef unsigned short ushort;
typedef __attribute__((ext_vector_type(8))) short short8v;
typedef __attribute__((ext_vector_type(4))) float f32x4;

#define NBMAX 512      // max coarse buckets (bucket = 256 nodes, N <= 131072)
#define BSHIFT 8       // 256 nodes per bucket

__device__ __forceinline__ ushort f2bf(float f) {
    uint u = __float_as_uint(f);
    u += 0x7fffu + ((u >> 16) & 1u);   // round-to-nearest-even
    return (ushort)(u >> 16);
}

// ---------------- binned CSR build ----------------
// Pass A hist (+ W1/W2 transpose/convert/swizzle piggybacked; bcnt pre-zeroed by memset).

__global__ void hist_prep(const int* __restrict__ dst, int* __restrict__ bcnt,
                          int E, int nbk,
                          const float* __restrict__ W1, const float* __restrict__ W2,
                          ushort* __restrict__ Wt1s, ushort* __restrict__ Wt2s) {
    __shared__ int s[NBMAX];
    int t = threadIdx.x;
    for (int i = t; i < nbk; i += 256) s[i] = 0;
    __syncthreads();
    int i0 = blockIdx.x * 4096 + t;
#pragma unroll
    for (int k = 0; k < 16; ++k) {
        int i = i0 + k * 256;
        if (i < E) atomicAdd(&s[dst[i] >> BSHIFT], 1);
    }
    __syncthreads();
    for (int i = t; i < nbk; i += 256) if (s[i] > 0) atomicAdd(&bcnt[i], s[i]);

    // W images: [n][k] bf16, byte ^ ((n&7)<<4)
    int g = blockIdx.x * 256 + t;
    int total = gridDim.x * 256;
    for (int idx = g; idx < 128 * 128; idx += total) {
        int nn = idx >> 7, kk = idx & 127;
        uint byte = (uint)nn * 256u + (uint)kk * 2u;
        byte ^= (uint)((nn & 7) << 4);
        Wt1s[byte >> 1] = f2bf(W1[kk * 128 + nn]);
    }
    for (int idx = g; idx < 64 * 128; idx += total) {
        int nn = idx >> 7, kk = idx & 127;
        uint byte = (uint)nn * 256u + (uint)kk * 2u;
        byte ^= (uint)((nn & 7) << 4);
        Wt2s[byte >> 1] = f2bf(W2[kk * 64 + nn]);
    }
}

// single block, 512 threads: exclusive scan bcnt -> bstart (kept) and bcur (mutated later)
__global__ void bucket_scan(const int* __restrict__ bcnt, int* __restrict__ bstart,
                            int* __restrict__ bcur, int nbk) {
    __shared__ int s[512];
    int t = threadIdx.x;
    int v = (t < nbk) ? bcnt[t] : 0;
    s[t] = v;
    __syncthreads();
    for (int o = 1; o < 512; o <<= 1) {
        int tv = (t >= o) ? s[t - o] : 0;
        __syncthreads();
        s[t] += tv;
        __syncthreads();
    }
    if (t < nbk) {
        int ex = s[t] - v;
        bstart[t] = ex;
        bcur[t] = ex;
    }
}

__global__ void bucket_scatter(const int* __restrict__ src, const int* __restrict__ dst,
                               int* __restrict__ bcur, int* __restrict__ tsw, int E) {
    __shared__ int cnt[NBMAX];
    __shared__ int base[NBMAX];
    int t = threadIdx.x;
    for (int i = t; i < NBMAX; i += 256) cnt[i] = 0;
    __syncthreads();
    int i0 = blockIdx.x * 4096 + t;
    int p_[16], b_[16], r_[16];
#pragma unroll
    for (int k = 0; k < 16; ++k) {
        int i = i0 + k * 256;
        if (i < E) {
            int s = src[i], d = dst[i];
            int bb = d >> BSHIFT;
            b_[k] = bb;
            p_[k] = s | ((d & ((1 << BSHIFT) - 1)) << 17);
            r_[k] = atomicAdd(&cnt[bb], 1);
        } else {
            b_[k] = -1;
        }
    }
    __syncthreads();
    for (int i = t; i < NBMAX; i += 256) if (cnt[i] > 0) base[i] = atomicAdd(&bcur[i], cnt[i]);
    __syncthreads();
#pragma unroll
    for (int k = 0; k < 16; ++k) {
        if (b_[k] >= 0) {
            int p = base[b_[k]] + r_[k];
            tsw[p] = p_[k];
        }
    }
}

// Pass B: one block per bucket. LDS counting-sort by local dst; the LDS histogram IS
// the in-degree -> emits dinv, rp, self-loops, and the bucket's contiguous edata region.
__global__ void sort_bucket(const int* __restrict__ tsw, const int* __restrict__ bstart,
                            float* __restrict__ dinv, int* __restrict__ rp,
                            int* __restrict__ edata, int N, int E, int nbk) {
    __shared__ int cnt[256];
    __shared__ int cursor[256];
    int b = blockIdx.x;
    int t = threadIdx.x;
    int estart = bstart[b];
    int eend = (b + 1 < nbk) ? bstart[b + 1] : E;

    cnt[t] = 0;
    __syncthreads();
    for (int i = estart + t; i < eend; i += 256) {
        atomicAdd(&cnt[(uint)tsw[i] >> 17], 1);
    }
    __syncthreads();

    int node = (b << BSHIFT) + t;
    int self = (node < N) ? 1 : 0;
    int deg = cnt[t];
    int v = deg + self;
    cursor[t] = v;
    __syncthreads();
    for (int o = 1; o < 256; o <<= 1) {
        int tv = (t >= o) ? cursor[t - o] : 0;
        __syncthreads();
        cursor[t] += tv;
        __syncthreads();
    }
    int ex = cursor[t] - v;                       // exclusive local offset
    int gbase = estart + (b << BSHIFT);           // edges + self loops before this bucket

    if (node < N) {
        dinv[node] = rsqrtf((float)(deg + 1));    // + self loop
        rp[node] = gbase + ex;
        edata[gbase + ex] = node;                 // self loop at slot 0 (src == dst)
    }
    if (b == nbk - 1 && t == 0) rp[N] = E + N;
    cursor[t] = ex + self;
    __syncthreads();

    for (int i = estart + t; i < eend; i += 256) {
        uint rec = (uint)tsw[i];
        int pos = gbase + atomicAdd(&cursor[rec >> 17], 1);
        edata[pos] = (int)(rec & 0x1FFFFu);
    }
}

// ---------------- MFMA GEMM layer 1: H1[row][0..128) = dinv[row] * (X[row] @ W1) ----------------
// Zeroes the pad row at index n (blockIdx 0).
// mfma_f32_16x16x32_bf16: A row=lane&15, k=(lane>>4)*8+i ; B col=lane&15, same k ;
// D col=lane&15, row=(lane>>4)*4+reg

__launch_bounds__(256)
__global__ void gemm_mfma128(const float* __restrict__ X, const ushort* __restrict__ Wimg,
                             ushort* __restrict__ H, const float* __restrict__ dinv, int n) {
    constexpr int NT = 8;
    if (blockIdx.x == 0 && threadIdx.x < 128) H[(size_t)n * 128 + threadIdx.x] = 0;
    __shared__ ushort sW[128 * 128];
    {
        const uint4* src = (const uint4*)Wimg;
        uint4* dst = (uint4*)sW;
        for (int i = threadIdx.x; i < 128 * 128 * 2 / 16; i += 256) dst[i] = src[i];
    }
    __syncthreads();

    const int w  = threadIdx.x >> 6;
    const int l  = threadIdx.x & 63;
    const int lm = l & 15, lk = l >> 4;
    const int row_base = blockIdx.x * 128 + w * 32;

    f32x4 acc[2][NT];
#pragma unroll
    for (int mt = 0; mt < 2; ++mt)
#pragma unroll
        for (int nt = 0; nt < NT; ++nt) {
            f32x4 z = {0.f, 0.f, 0.f, 0.f};
            acc[mt][nt] = z;
        }

    int r0 = row_base + lm;
    int r1 = row_base + 16 + lm;
    int r0c = r0 < n ? r0 : n - 1;
    int r1c = r1 < n ? r1 : n - 1;

#pragma unroll
    for (int kb = 0; kb < 4; ++kb) {
        short8v a0, a1;
        const float* p0 = X + (size_t)r0c * 128 + kb * 32 + lk * 8;
        const float* p1 = X + (size_t)r1c * 128 + kb * 32 + lk * 8;
        float4 u0 = *(const float4*)p0;
        float4 v0 = *(const float4*)(p0 + 4);
        float4 u1 = *(const float4*)p1;
        float4 v1 = *(const float4*)(p1 + 4);
        a0[0] = (short)f2bf(u0.x); a0[1] = (short)f2bf(u0.y);
        a0[2] = (short)f2bf(u0.z); a0[3] = (short)f2bf(u0.w);
        a0[4] = (short)f2bf(v0.x); a0[5] = (short)f2bf(v0.y);
        a0[6] = (short)f2bf(v0.z); a0[7] = (short)f2bf(v0.w);
        a1[0] = (short)f2bf(u1.x); a1[1] = (short)f2bf(u1.y);
        a1[2] = (short)f2bf(u1.z); a1[3] = (short)f2bf(u1.w);
        a1[4] = (short)f2bf(v1.x); a1[5] = (short)f2bf(v1.y);
        a1[6] = (short)f2bf(v1.z); a1[7] = (short)f2bf(v1.w);
#pragma unroll
        for (int nt = 0; nt < NT; ++nt) {
            int nn = nt * 16 + lm;
            uint byte = (uint)nn * 256u + (uint)kb * 64u + (uint)lk * 16u;
            byte ^= (uint)((nn & 7) << 4);
            short8v b = *(const short8v*)((const char*)sW + byte);
            acc[0][nt] = __builtin_amdgcn_mfma_f32_16x16x32_bf16(a0, b, acc[0][nt], 0, 0, 0);
            acc[1][nt] = __builtin_amdgcn_mfma_f32_16x16x32_bf16(a1, b, acc[1][nt], 0, 0, 0);
        }
    }

    float dvs[2][4];
#pragma unroll
    for (int mt = 0; mt < 2; ++mt)
#pragma unroll
        for (int r = 0; r < 4; ++r) {
            int row = row_base + mt * 16 + lk * 4 + r;
            dvs[mt][r] = (row < n) ? dinv[row] : 0.f;
        }
#pragma unroll
    for (int mt = 0; mt < 2; ++mt)
#pragma unroll
        for (int nt = 0; nt < NT; ++nt)
#pragma unroll
            for (int r = 0; r < 4; ++r) {
                int row = row_base + mt * 16 + lk * 4 + r;
                if (row < n) H[(size_t)row * 128 + nt * 16 + lm] = f2bf(acc[mt][nt][r] * dvs[mt][r]);
            }
}

// ---------------- fused layer-1 agg + layer-2 GEMM ----------------
// Gather phase (as round-12 agg128): 16-lane quarter per node, uint4/lane, 16 loads
// in flight; computes A1row = relu(dinv[node]*sum H1[src] + b1) in registers.
// Pack to bf16 -> swizzled LDS tile sA[16][128]; barrier; each wave MFMAs the 16-node
// tile against W2 (LDS image) for its 16-col n-tile; writes H2 = dinv*(A1@W2).

__launch_bounds__(256)
__global__ void agg128_w2(const ushort* __restrict__ H, const int* __restrict__ rp,
                          const int* __restrict__ edata, const float* __restrict__ dinv,
                          const float* __restrict__ b1, const ushort* __restrict__ W2img,
                          ushort* __restrict__ H2, int N) {
    __shared__ ushort sW[64 * 128];   // 16KB W2 image (swizzled)
    __shared__ ushort sA[16 * 128];   // 4KB A1 tile (swizzled)
    {
        const uint4* s = (const uint4*)W2img;
        uint4* d = (uint4*)sW;
        for (int i = threadIdx.x; i < 64 * 128 * 2 / 16; i += 256) d[i] = s[i];
    }
    if (blockIdx.x == 0 && threadIdx.x < 64) H2[(size_t)N * 64 + threadIdx.x] = 0;

    const int lane = threadIdx.x & 63;
    const int c = lane & 15;                      // lane in quarter
    const int qb = lane & 48;                     // quarter base within wave
    const int nl = threadIdx.x >> 4;              // local node 0..15
    const int node = blockIdx.x * 16 + nl;

    float a0 = 0.f, a1 = 0.f, a2 = 0.f, a3 = 0.f;
    float a4 = 0.f, a5 = 0.f, a6 = 0.f, a7 = 0.f;

    if (node < N) {
        int e = rp[node], end = rp[node + 1];
        for (; e < end; e += 16) {
            int idx = e + c;
            int md = (idx < end) ? edata[idx] : N;    // zero row for padding slots
#pragma unroll
            for (int j = 0; j < 16; ++j) {
                int si = __shfl(md, qb + j);
                uint4 hv = *(const uint4*)&H[(size_t)si * 128 + c * 8];
                a0 += __uint_as_float(hv.x << 16);
                a1 += __uint_as_float(hv.x & 0xffff0000u);
                a2 += __uint_as_float(hv.y << 16);
                a3 += __uint_as_float(hv.y & 0xffff0000u);
                a4 += __uint_as_float(hv.z << 16);
                a5 += __uint_as_float(hv.z & 0xffff0000u);
                a6 += __uint_as_float(hv.w << 16);
                a7 += __uint_as_float(hv.w & 0xffff0000u);
            }
        }
        float dg = dinv[node];
        float4 bv0 = *(const float4*)&b1[c * 8];
        float4 bv1 = *(const float4*)&b1[c * 8 + 4];
        a0 = fmaxf(dg * a0 + bv0.x, 0.f); a1 = fmaxf(dg * a1 + bv0.y, 0.f);
        a2 = fmaxf(dg * a2 + bv0.z, 0.f); a3 = fmaxf(dg * a3 + bv0.w, 0.f);
        a4 = fmaxf(dg * a4 + bv1.x, 0.f); a5 = fmaxf(dg * a5 + bv1.y, 0.f);
        a6 = fmaxf(dg * a6 + bv1.z, 0.f); a7 = fmaxf(dg * a7 + bv1.w, 0.f);
    } else {
        a0 = a1 = a2 = a3 = a4 = a5 = a6 = a7 = 0.f;   // zero A rows for pad nodes
    }
    uint4 pk;
    pk.x = (uint)f2bf(a0) | ((uint)f2bf(a1) << 16);
    pk.y = (uint)f2bf(a2) | ((uint)f2bf(a3) << 16);
    pk.z = (uint)f2bf(a4) | ((uint)f2bf(a5) << 16);
    pk.w = (uint)f2bf(a6) | ((uint)f2bf(a7) << 16);
    uint wbyte = (uint)nl * 256u + (((uint)c * 16u) ^ ((uint)(nl & 7) << 4));
    *(uint4*)((char*)sA + wbyte) = pk;
    __syncthreads();

    // MFMA: 16 nodes x 128k @ 128k x 64 -> wave w computes cols [w*16, w*16+16)
    const int w  = threadIdx.x >> 6;
    const int lm = lane & 15, lk = lane >> 4;
    const int nn = w * 16 + lm;
    f32x4 acc = {0.f, 0.f, 0.f, 0.f};
#pragma unroll
    for (int kb = 0; kb < 4; ++kb) {
        uint ka = (uint)(kb * 64 + lk * 16);
        short8v af = *(const short8v*)((const char*)sA + (uint)lm * 256u + (ka ^ ((uint)(lm & 7) << 4)));
        short8v bf = *(const short8v*)((const char*)sW + (uint)nn * 256u + (ka ^ ((uint)(nn & 7) << 4)));
        acc = __builtin_amdgcn_mfma_f32_16x16x32_bf16(af, bf, acc, 0, 0, 0);
    }
#pragma unroll
    for (int r = 0; r < 4; ++r) {
        int n2 = blockIdx.x * 16 + lk * 4 + r;
        if (n2 < N) H2[(size_t)n2 * 64 + w * 16 + lm] = f2bf(acc[r] * dinv[n2]);
    }
}

// ---------------- layer-2 aggregation (unchanged round-12 agg64) ----------------
// H2 is [N+1][64] bf16 (pre-scaled by dinv[src]) with zero pad row at N.
// out[node] = dinv[node] * sum_e H2[src_e] + b2; fp32 out.

__launch_bounds__(256)
__global__ void agg64(const ushort* __restrict__ H, const int* __restrict__ rp,
                      const int* __restrict__ edata, const float* __restrict__ dinv,
                      const float* __restrict__ bias, float* __restrict__ out, int N) {
    const int lane = threadIdx.x & 63;
    const int qb = lane & 48;
    const int c = lane & 15;
    const int node = blockIdx.x * 16 + (threadIdx.x >> 4);
    if (node >= N) return;
    int e = rp[node], end = rp[node + 1];
    float a0 = 0.f, a1 = 0.f, a2 = 0.f, a3 = 0.f;

    for (; e < end; e += 16) {
        int idx = e + c;
        int md = (idx < end) ? edata[idx] : N;
#pragma unroll
        for (int j = 0; j < 16; ++j) {
            int si = __shfl(md, qb + j);
            uint2 hv = *(const uint2*)&H[(size_t)si * 64 + c * 4];
            a0 += __uint_as_float(hv.x << 16);
            a1 += __uint_as_float(hv.x & 0xffff0000u);
            a2 += __uint_as_float(hv.y << 16);
            a3 += __uint_as_float(hv.y & 0xffff0000u);
        }
    }
    float dg = dinv[node];
    float4 bv = *(const float4*)&bias[c * 4];
    a0 = dg * a0 + bv.x; a1 = dg * a1 + bv.y;
    a2 = dg * a2 + bv.z; a3 = dg * a3 + bv.w;
    *(float4*)&out[(size_t)node * 64 + c * 4] = make_float4(a0, a1, a2, a3);
}

__global__ void zero_out(float* __restrict__ out, int n) {
    int i = blockIdx.x * 256 + threadIdx.x;
    if (i < n) out[i] = 0.f;
}

// ---------------- launch ----------------

extern "C" void kernel_launch(void* const* d_in, const int* in_sizes, int n_in,
                              void* d_out, int out_size, void* d_ws, size_t ws_size,
                              hipStream_t stream) {
    const float* x  = (const float*)d_in[0];
    const int*   ei = (const int*)d_in[1];
    const float* W1 = (const float*)d_in[2];
    const float* b1 = (const float*)d_in[3];
    const float* W2 = (const float*)d_in[4];
    const float* b2 = (const float*)d_in[5];
    float* out = (float*)d_out;

    const int N = in_sizes[0] / 128;
    const int E = in_sizes[1] / 2;
    const int* srcp = ei;
    const int* dstp = ei + E;

    char* base = (char*)d_ws;
    size_t off = 0;
    auto alloc = [&](size_t bytes) -> void* {
        void* p = base + off;
        off += (bytes + 15) & ~(size_t)15;
        return p;
    };
    ushort* H1    = (ushort*)alloc((size_t)(N + 1) * 128 * 2);  // [N+1][128] + pad row
    ushort* H2    = (ushort*)alloc((size_t)(N + 1) * 64 * 2);   // [N+1][64] + pad row; aliases tsw
    ushort* Wt1s  = (ushort*)alloc(128 * 128 * 2);
    ushort* Wt2s  = (ushort*)alloc(64 * 128 * 2);
    float*  dinv  = (float*)alloc((size_t)N * 4);
    int*    rp    = (int*)alloc((size_t)(N + 1) * 4);
    int*    bcnt  = (int*)alloc(NBMAX * 4);
    int*    bstart= (int*)alloc(NBMAX * 4);
    int*    bcur  = (int*)alloc(NBMAX * 4);
    int*    edata = (int*)alloc((size_t)(E + N) * 4);

    int* tsw = (int*)H2;   // E records of 4B, dead before agg128_w2 writes H2

    int nbk = (N + (1 << BSHIFT) - 1) >> BSHIFT;
    if (off > ws_size || (size_t)E * 4 > (size_t)(N + 1) * 128 ||
        N > (1 << 17) || nbk > NBMAX) {
        zero_out<<<(out_size + 255) / 256, 256, 0, stream>>>(out, out_size);
        return;
    }
    int nchunk = (E + 4095) / 4096;

    hipMemsetAsync(bcnt, 0, NBMAX * sizeof(int), stream);
    hist_prep<<<nchunk, 256, 0, stream>>>(dstp, bcnt, E, nbk, W1, W2, Wt1s, Wt2s);
    bucket_scan<<<1, 512, 0, stream>>>(bcnt, bstart, bcur, nbk);
    bucket_scatter<<<nchunk, 256, 0, stream>>>(srcp, dstp, bcur, tsw, E);
    sort_bucket<<<nbk, 256, 0, stream>>>(tsw, bstart, dinv, rp, edata, N, E, nbk);

    gemm_mfma128<<<(N + 127) / 128, 256, 0, stream>>>(x, Wt1s, H1, dinv, N);
    agg128_w2<<<(N + 15) / 16, 256, 0, stream>>>(H1, rp, edata, dinv, b1, Wt2s, H2, N);
    agg64<<<(N + 15) / 16, 256, 0, stream>>>(H2, rp, edata, dinv, b2, out, N);
}